// Round 13
// baseline (228.120 us; speedup 1.0000x reference)
//
#include <hip/hip_runtime.h>
#include <math.h>

#define BN 32
#define LL 1024
#define HH 128

typedef __attribute__((ext_vector_type(8))) short short8;
typedef __attribute__((ext_vector_type(4))) float f32x4;

static const size_t SZ_BF = (size_t)BN * LL * HH * 2;  // one bf16 matrix = 8 MB

__device__ __forceinline__ ushort f2bf(float x) {
  union { float f; unsigned u; } c; c.f = x;
  unsigned r = c.u + 0x7fffu + ((c.u >> 16) & 1u);
  return (ushort)(r >> 16);
}
__device__ __forceinline__ float bf2f(ushort h) {
  union { unsigned u; float f; } c; c.u = ((unsigned)h) << 16;
  return c.f;
}
__device__ __forceinline__ short8 ld8(const ushort* p) {
  return *(const short8*)p;
}

// ---------------------------------------------------------------------------
// Chunked MFMA-ready layouts (R11-measured: k_features 87->60 us).
//   S-chunks (abfs/bbfs):  chunk(bb, g, k), g = row/16, k = d/32;
//   T-chunks (aTs/bTs):    chunk(bb, dg, mb), dg = d/16, mb = m/32.
// Every hot-loop operand load = ONE contiguous 1KB ld8 at base+lane*16B.
// ---------------------------------------------------------------------------
__device__ __forceinline__ size_t chunkS(int bb, int g, int k) {
  return (((size_t)bb * 64 + g) * 4 + k) * 512;
}
__device__ __forceinline__ size_t chunkT(int bb, int dg, int mb) {
  return (((size_t)bb * 8 + dg) * 32 + mb) * 512;
}

// ---------------------------------------------------------------------------
// k_convert: f32 -> bf16 chunked copies abfs,bbfs (S-operand order) and
// aTs,bTs (F-operand order). Fused means as before.  (unchanged, R11)
// grid (16 l-tiles, 32 batches, 2 which), block 256.
// ---------------------------------------------------------------------------
__global__ __launch_bounds__(256) void k_convert(
    const float* __restrict__ a, const float* __restrict__ b,
    const int* __restrict__ mask_b,
    ushort* __restrict__ abfs, ushort* __restrict__ bbfs,
    ushort* __restrict__ aTs, ushort* __restrict__ bTs,
    float* __restrict__ meanb, float* __restrict__ invmean) {
  int bb = blockIdx.y;
  int l0 = blockIdx.x * 64;
  int which = blockIdx.z;              // 0 -> a (->invmean), 1 -> b (->meanb)
  const float* src = which ? b : a;
  ushort* dstS = which ? bbfs : abfs;
  ushort* dstT = which ? bTs : aTs;
  float* dmean = which ? meanb : invmean;
  __shared__ __align__(16) ushort T[128][72];  // [d][l], padded
  __shared__ float accS[128];
  __shared__ float wgt[64];
  int t = threadIdx.x;
  if (t < 128) accS[t] = 0.f;
  if (t < 64)
    wgt[t] = which ? 1.0f : ((mask_b[bb * LL + l0 + t] == 0) ? 1.0f : 0.0f);
  int lrow = t >> 5;         // 0..7
  int dcol = (t & 31) * 4;   // 0..124
#pragma unroll
  for (int p = 0; p < 8; ++p) {
    int l = p * 8 + lrow;    // local row 0..63
    float4 v = *(const float4*)&src[((size_t)bb * LL + l0 + l) * HH + dcol];
    ushort4 u;
    u.x = f2bf(v.x); u.y = f2bf(v.y); u.z = f2bf(v.z); u.w = f2bf(v.w);
    int g = (l0 >> 4) + (l >> 4);
    int k = dcol >> 5, quadc = (dcol >> 3) & 3, j = dcol & 7;
    *(ushort4*)&dstS[chunkS(bb, g, k) + (size_t)(quadc * 16 + (l & 15)) * 8 + j] = u;
    T[dcol + 0][l] = u.x; T[dcol + 1][l] = u.y;
    T[dcol + 2][l] = u.z; T[dcol + 3][l] = u.w;
  }
  __syncthreads();
#pragma unroll
  for (int c = 0; c < 4; ++c) {
    int cid = c * 4 + (t >> 6);        // 0..15
    int dg = cid >> 1, mloc = cid & 1;
    int lane = t & 63, l16c = lane & 15, qc = lane >> 4;
    int row = dg * 16 + l16c, colb = mloc * 32 + qc * 8;
    uint2 vlo = *(const uint2*)&T[row][colb];
    uint2 vhi = *(const uint2*)&T[row][colb + 4];
    union { uint4 u4; short8 s8; ushort us[8]; } cv_;
    cv_.u4 = make_uint4(vlo.x, vlo.y, vhi.x, vhi.y);
    *(short8*)&dstT[chunkT(bb, dg, (l0 >> 5) + mloc) + (size_t)lane * 8] = cv_.s8;
    float s = 0.f;
#pragma unroll
    for (int jj = 0; jj < 8; ++jj) s += wgt[colb + jj] * bf2f(cv_.us[jj]);
    atomicAdd(&accS[row], s);
  }
  __syncthreads();
  if (t < 128) atomicAdd(&dmean[bb * HH + t], accS[t]);
}

// ---------------------------------------------------------------------------
// Batch-co-locating swizzle, 32-tile variant (R13): grid 1024;
// xcd = wg&7, j = wg>>3 (0..127), tile = j&31, bb = (j>>5)*8 + xcd.
// All 32 tiles of batch bb still share XCD bb&7 (R8-measured mechanism).
// ---------------------------------------------------------------------------

// ---------------------------------------------------------------------------
// k_colsum R13: m-tile 64->32 (Bm regs halved), grid 1024, lb(256,4)
//   -> 4 blocks/CU. Chunked loads + Pb-fold epilogue (R11-measured) kept;
//   Pb-fold slice = exactly one 32-m chunk column (disjoint per block).
// grid 1024 (1-D swizzled), block 256.
// ---------------------------------------------------------------------------
__global__ __launch_bounds__(256, 4) void k_colsum(
    const ushort* __restrict__ abfs, const ushort* __restrict__ bbfs,
    ushort* __restrict__ aTm,            // non-const: scaled in place
    const int* __restrict__ mask_a, const int* __restrict__ mask_b,
    const float* __restrict__ temp_p, float2* __restrict__ cc) {
  int wg = blockIdx.x;
  int xcd = wg & 7, j_ = wg >> 3;
  int bb = (j_ >> 5) * 8 + xcd;
  int m0 = (j_ & 31) * 32;
  int t = threadIdx.x;
  int w = t >> 6, lane = t & 63, l16 = lane & 15, quad = lane >> 4;
  float temp = temp_p[0];
  __shared__ __align__(16) float biasA[LL];
  __shared__ float csred[4][2][16];
  __shared__ float invS[32];
  for (int i = t; i < LL; i += 256)
    biasA[i] = mask_a[bb * LL + i] ? 0.0f : -10000.0f;

  short8 Bm[2][4];
  float biasB_mt[2];
#pragma unroll
  for (int mt = 0; mt < 2; ++mt) {
    int m = m0 + mt * 16 + l16;
    biasB_mt[mt] = mask_b[bb * LL + m] ? 0.0f : -10000.0f;
#pragma unroll
    for (int k = 0; k < 4; ++k)
      Bm[mt][k] = ld8(&bbfs[chunkS(bb, (m0 >> 4) + mt, k) + (size_t)lane * 8]);
  }
  __syncthreads();

  float cs[2] = {0.f, 0.f};
  short8 Al0[4], Al1[4];

#define LOADAL(AlX, IT)                                                       \
  {                                                                           \
    _Pragma("unroll") for (int k = 0; k < 4; ++k)                             \
        AlX[k] = ld8(&abfs[chunkS(bb, w * 16 + (IT), k) + (size_t)lane * 8]); \
  }

#define CSCOMPUTE(AlX, IT)                                                    \
  {                                                                           \
    int lbase = w * 256 + (IT) * 16;                                          \
    f32x4 bA = *(const f32x4*)&biasA[lbase + quad * 4];                       \
    _Pragma("unroll") for (int mt = 0; mt < 2; ++mt) {                        \
      f32x4 sacc = {0.f, 0.f, 0.f, 0.f};                                      \
      _Pragma("unroll") for (int k = 0; k < 4; ++k)                           \
          sacc = __builtin_amdgcn_mfma_f32_16x16x32_bf16(AlX[k], Bm[mt][k],   \
                                                         sacc, 0, 0, 0);      \
      _Pragma("unroll") for (int r = 0; r < 4; ++r)                           \
          cs[mt] += __expf(sacc[r] * temp + bA[r] + biasB_mt[mt]);            \
    }                                                                         \
  }

  LOADAL(Al0, 0);
  for (int it = 0; it < 16; it += 2) {
    LOADAL(Al1, it + 1);
    CSCOMPUTE(Al0, it);
    LOADAL(Al0, (it + 2) & 15);   // last prefetch wraps to 0 (unused, in-bounds)
    CSCOMPUTE(Al1, it + 1);
  }
#undef LOADAL
#undef CSCOMPUTE

#pragma unroll
  for (int mt = 0; mt < 2; ++mt) {
    cs[mt] += __shfl_xor(cs[mt], 16);
    cs[mt] += __shfl_xor(cs[mt], 32);
  }
  if (lane < 16) {
#pragma unroll
    for (int mt = 0; mt < 2; ++mt) csred[w][mt][l16] = cs[mt];
  }
  __syncthreads();
  if (t < 32) {
    int mt = t >> 4, ml = t & 15;
    float s = csred[0][mt][ml] + csred[1][mt][ml] + csred[2][mt][ml] + csred[3][mt][ml];
    int m = m0 + t;
    float bB = mask_b[bb * LL + m] ? 0.0f : -10000.0f;
    float inv = s > 0.f ? 1.0f / s : 0.0f;
    invS[t] = inv;
    cc[bb * LL + m] = make_float2(inv, bB);
  }
  __syncthreads();

  // ---- Pb-fold epilogue: scale this block's 8 aTs chunks (one 32-m col) ----
#pragma unroll
  for (int c = 0; c < 2; ++c) {
    int dg = c * 4 + (t >> 6);         // 0..7
    int ln = t & 63;
    ushort* ap = &aTm[chunkT(bb, dg, m0 >> 5) + (size_t)ln * 8];
    short8 v = ld8(ap);
    int mb = (ln >> 4) * 8;            // local m base within 32-slice
    ushort o[8];
#pragma unroll
    for (int jj = 0; jj < 8; ++jj) o[jj] = f2bf(bf2f((ushort)v[jj]) * invS[mb + jj]);
    *(short8*)ap = *(short8*)&o[0];
  }
}

// ---------------------------------------------------------------------------
// k_features R13: R11 structure exactly (chunk loads, single-P Pb-fold,
//   S||F pipeline skeleton with __syncthreads, swizzle, NT stores) with
//   l-tile 64->32: acc/Afix halved, grid 1024, lb(256,4) -> 4 blocks/CU,
//   ~16 waves/CU (occupancy was grid-limited at 2 blocks/CU).
// grid 1024 (1-D swizzled), block 256.
// ---------------------------------------------------------------------------
__global__ __launch_bounds__(256, 4) void k_features(
    const ushort* __restrict__ abfs, const ushort* __restrict__ bbfs,
    const ushort* __restrict__ aTs, const ushort* __restrict__ bTs,
    const int* __restrict__ mask_a, const float* __restrict__ temp_p,
    const float2* __restrict__ cc, const float* __restrict__ meanb,
    const float* __restrict__ invmean, float* __restrict__ out) {
  int wg = blockIdx.x;
  int xcd = wg & 7, j_ = wg >> 3;
  int bb = (j_ >> 5) * 8 + xcd;
  int l0 = (j_ & 31) * 32;
  int t = threadIdx.x;
  int w = t >> 6, lane = t & 63, l16 = lane & 15, quad = lane >> 4;
  float temp = temp_p[0];

  __shared__ float2 ccs[LL];                        // 8 KB (only .y used)
  __shared__ __align__(16) ushort Pa[2][32 * 72];   // double-buffered, 9.2 KB
  __shared__ float rspart[4][32];
  __shared__ float rsfin[32];

  for (int i = t; i < LL; i += 256) ccs[i] = cc[bb * LL + i];

  float biasA_lt[2];
  short8 Afix[2][4];   // abf rows l0..l0+31 as B-operands (32 VGPRs)
#pragma unroll
  for (int lt = 0; lt < 2; ++lt) {
    int l = l0 + lt * 16 + l16;
    biasA_lt[lt] = mask_a[bb * LL + l] ? 0.0f : -10000.0f;
#pragma unroll
    for (int k = 0; k < 4; ++k)
      Afix[lt][k] = ld8(&abfs[chunkS(bb, (l0 >> 4) + lt, k) + (size_t)lane * 8]);
  }

  f32x4 accA[2][2], accB[2][2];
  f32x4 zero = {0.f, 0.f, 0.f, 0.f};
#pragma unroll
  for (int lt = 0; lt < 2; ++lt)
#pragma unroll
    for (int dt = 0; dt < 2; ++dt) { accA[lt][dt] = zero; accB[lt][dt] = zero; }
  float rs_lt[2] = {0.f, 0.f};
  __syncthreads();   // ccs ready

  short8 Am0[4], Am1[4];
  float cv0[4], cv1[4];                // biasB only
  short8 Bb0[2][2], Ba0[2][2], Bb1[2][2], Ba1[2][2];

#define LOADAM(AmX, cvX, M0)                                                  \
  {                                                                           \
    _Pragma("unroll") for (int k = 0; k < 4; ++k)                             \
        AmX[k] = ld8(&bbfs[chunkS(bb, ((M0) >> 4) + w, k) + (size_t)lane * 8]); \
    _Pragma("unroll") for (int r = 0; r < 4; ++r)                             \
        cvX[r] = ccs[(M0) + w * 16 + quad * 4 + r].y;                         \
  }

#define LOADBT(BbX, BaX, M0)                                                  \
  {                                                                           \
    _Pragma("unroll") for (int dt = 0; dt < 2; ++dt) {                        \
      _Pragma("unroll") for (int ks = 0; ks < 2; ++ks) {                      \
        size_t cb = chunkT(bb, w * 2 + dt, ((M0) >> 5) + ks) + (size_t)lane * 8; \
        BbX[dt][ks] = ld8(&bTs[cb]);                                          \
        BaX[dt][ks] = ld8(&aTs[cb]);                                          \
      }                                                                       \
    }                                                                         \
  }

// S-phase writing P[PBUFI] (single Pa buffer: e only)
#define SPHASE(AmX, cvX, PBUFI)                                               \
  {                                                                           \
    ushort* pa = &Pa[PBUFI][0];                                               \
    _Pragma("unroll") for (int lt = 0; lt < 2; ++lt) {                        \
      f32x4 sacc = zero;                                                      \
      _Pragma("unroll") for (int k = 0; k < 4; ++k)                           \
          sacc = __builtin_amdgcn_mfma_f32_16x16x32_bf16(AmX[k], Afix[lt][k], \
                                                         sacc, 0, 0, 0);      \
      ushort pav[4];                                                          \
      _Pragma("unroll") for (int r = 0; r < 4; ++r) {                         \
        float e = __expf(sacc[r] * temp + biasA_lt[lt] + cvX[r]);             \
        pav[r] = f2bf(e);                                                     \
        rs_lt[lt] += bf2f(pav[r]);                                            \
      }                                                                       \
      uint2 ka;                                                               \
      ka.x = (uint)pav[0] | ((uint)pav[1] << 16);                             \
      ka.y = (uint)pav[2] | ((uint)pav[3] << 16);                             \
      int pidx = (lt * 16 + l16) * 72 + w * 16 + quad * 4;                    \
      *(uint2*)&pa[pidx] = ka;                                                \
    }                                                                         \
  }

// F-phase reading P[PBUFI]; PaF shared by accA (x Bb) and accB (x Ba)
#define FPHASE(PBUFI, BbX, BaX)                                               \
  {                                                                           \
    const ushort* pa = &Pa[PBUFI][0];                                         \
    _Pragma("unroll") for (int lt = 0; lt < 2; ++lt) {                        \
      _Pragma("unroll") for (int ks = 0; ks < 2; ++ks) {                      \
        int ridx = (lt * 16 + l16) * 72 + ks * 32 + quad * 8;                 \
        short8 PaF = *(const short8*)&pa[ridx];                               \
        _Pragma("unroll") for (int dt = 0; dt < 2; ++dt) {                    \
          accA[lt][dt] = __builtin_amdgcn_mfma_f32_16x16x32_bf16(             \
              PaF, BbX[dt][ks], accA[lt][dt], 0, 0, 0);                       \
          accB[lt][dt] = __builtin_amdgcn_mfma_f32_16x16x32_bf16(             \
              PaF, BaX[dt][ks], accB[lt][dt], 0, 0, 0);                       \
        }                                                                     \
      }                                                                       \
    }                                                                         \
  }

  // ---- prologue: S(T0) -> P[0] ----
  LOADAM(Am0, cv0, 0);
  LOADBT(Bb0, Ba0, 0);            // F operands tile 0 (consumed next interval)
  LOADAM(Am1, cv1, 64);           // S operands tile 1
  SPHASE(Am0, cv0, 0);
  __syncthreads();

  // ---- main loop: 7x {S(T_{2k+1})+F(T_{2k}); S(T_{2k+2})+F(T_{2k+1})} ----
  for (int kk = 0; kk < 7; ++kk) {
    int mA = (2 * kk + 1) * 64;
    LOADBT(Bb1, Ba1, mA);
    LOADAM(Am0, cv0, mA + 64);
    SPHASE(Am1, cv1, 1);
    FPHASE(0, Bb0, Ba0);
    __syncthreads();
    LOADBT(Bb0, Ba0, mA + 64);
    LOADAM(Am1, cv1, mA + 128);   // k=6 -> T15
    SPHASE(Am0, cv0, 0);
    FPHASE(1, Bb1, Ba1);
    __syncthreads();
  }

  // ---- epilogue: S(T15) -> P[1]; F(T14); barrier; F(T15) ----
  LOADBT(Bb1, Ba1, 960);
  SPHASE(Am1, cv1, 1);
  FPHASE(0, Bb0, Ba0);
  __syncthreads();
  FPHASE(1, Bb1, Ba1);

#undef LOADAM
#undef LOADBT
#undef SPHASE
#undef FPHASE

  // ---- rowsum cross-wave reduce ----
#pragma unroll
  for (int lt = 0; lt < 2; ++lt) {
    rs_lt[lt] += __shfl_xor(rs_lt[lt], 16);
    rs_lt[lt] += __shfl_xor(rs_lt[lt], 32);
  }
  if (lane < 16) {
#pragma unroll
    for (int lt = 0; lt < 2; ++lt) rspart[w][lt * 16 + l16] = rs_lt[lt];
  }
  __syncthreads();
  if (t < 32)
    rsfin[t] = rspart[0][t] + rspart[1][t] + rspart[2][t] + rspart[3][t];
  __syncthreads();

  // ---- epilogue: NON-TEMPORAL stores (bypass L2, keep panels resident) ----
  float* outA = out;
  float* outB = out + (size_t)BN * LL * HH;
#pragma unroll
  for (int dt = 0; dt < 2; ++dt) {
    int d = w * 32 + dt * 16 + l16;
    float mb = meanb[bb * HH + d] * (1.0f / 1024.0f);
    float im = invmean[bb * HH + d] * (1.0f / 1024.0f);
#pragma unroll
    for (int lt = 0; lt < 2; ++lt) {
#pragma unroll
      for (int r = 0; r < 4; ++r) {
        int l = lt * 16 + quad * 4 + r;
        float rsv = rsfin[l];
        float fa = (rsv > 0.f) ? accA[lt][dt][r] / rsv : mb;
        float fb = accB[lt][dt][r] + im;
        __builtin_nontemporal_store(fa, &outA[((size_t)bb * LL + l0 + l) * HH + d]);
        __builtin_nontemporal_store(fb, &outB[((size_t)bb * LL + l0 + l) * HH + d]);
      }
    }
  }
}

// ---------------------------------------------------------------------------
extern "C" void kernel_launch(void* const* d_in, const int* in_sizes, int n_in,
                              void* d_out, int out_size, void* d_ws, size_t ws_size,
                              hipStream_t stream) {
  const float* a = (const float*)d_in[0];
  const float* b = (const float*)d_in[1];
  const int* mask_a = (const int*)d_in[2];
  const int* mask_b = (const int*)d_in[3];
  const float* temp = (const float*)d_in[4];
  float* out = (float*)d_out;

  char* wsb = (char*)d_ws;
  ushort* abfs = (ushort*)(wsb + 0 * SZ_BF);
  ushort* bbfs = (ushort*)(wsb + 1 * SZ_BF);
  ushort* aTs  = (ushort*)(wsb + 2 * SZ_BF);
  ushort* bTs  = (ushort*)(wsb + 3 * SZ_BF);
  float2* cc  = (float2*)(wsb + 4 * SZ_BF);
  float* meanb   = (float*)(wsb + 4 * SZ_BF + (size_t)BN * LL * sizeof(float2));
  float* invmean = meanb + BN * HH;

  hipMemsetAsync(meanb, 0, 2 * BN * HH * sizeof(float), stream);
  k_convert<<<dim3(16, 32, 2), 256, 0, stream>>>(a, b, mask_b, abfs, bbfs, aTs,
                                                 bTs, meanb, invmean);
  k_colsum<<<dim3(1024), 256, 0, stream>>>(abfs, bbfs, aTs, mask_a, mask_b, temp, cc);
  k_features<<<dim3(1024), 256, 0, stream>>>(abfs, bbfs, aTs, bTs, mask_a, temp,
                                             cc, meanb, invmean, out);
  (void)in_sizes; (void)n_in; (void)out_size; (void)ws_size;
}

// Round 14
// 167.579 us; speedup vs baseline: 1.3613x; 1.3613x over previous
//
#include <hip/hip_runtime.h>
#include <math.h>

#define BN 32
#define LL 1024
#define HH 128

typedef __attribute__((ext_vector_type(8))) short short8;
typedef __attribute__((ext_vector_type(4))) float f32x4;

static const size_t SZ_BF = (size_t)BN * LL * HH * 2;  // one bf16 matrix = 8 MB

__device__ __forceinline__ ushort f2bf(float x) {
  union { float f; unsigned u; } c; c.f = x;
  unsigned r = c.u + 0x7fffu + ((c.u >> 16) & 1u);
  return (ushort)(r >> 16);
}
__device__ __forceinline__ float bf2f(ushort h) {
  union { unsigned u; float f; } c; c.u = ((unsigned)h) << 16;
  return c.f;
}
__device__ __forceinline__ short8 ld8(const ushort* p) {
  return *(const short8*)p;
}

// ---------------------------------------------------------------------------
// Chunked MFMA-ready layouts (R11-measured: k_features 87->60 us).
//   S-chunks (abfs/bbfs):  chunk(bb, g, k), g = row/16, k = d/32;
//   T-chunks (aTs/bTs):    chunk(bb, dg, mb), dg = d/16, mb = m/32.
// Every hot-loop operand load = ONE contiguous 1KB ld8 at base+lane*16B.
// ---------------------------------------------------------------------------
__device__ __forceinline__ size_t chunkS(int bb, int g, int k) {
  return (((size_t)bb * 64 + g) * 4 + k) * 512;
}
__device__ __forceinline__ size_t chunkT(int bb, int dg, int mb) {
  return (((size_t)bb * 8 + dg) * 32 + mb) * 512;
}

// ---------------------------------------------------------------------------
// k_convert: f32 -> bf16 chunked copies abfs,bbfs (S-operand order) and
// aTs,bTs (F-operand order). Fused means as before.  (unchanged, R11)
// grid (16 l-tiles, 32 batches, 2 which), block 256.
// ---------------------------------------------------------------------------
__global__ __launch_bounds__(256) void k_convert(
    const float* __restrict__ a, const float* __restrict__ b,
    const int* __restrict__ mask_b,
    ushort* __restrict__ abfs, ushort* __restrict__ bbfs,
    ushort* __restrict__ aTs, ushort* __restrict__ bTs,
    float* __restrict__ meanb, float* __restrict__ invmean) {
  int bb = blockIdx.y;
  int l0 = blockIdx.x * 64;
  int which = blockIdx.z;              // 0 -> a (->invmean), 1 -> b (->meanb)
  const float* src = which ? b : a;
  ushort* dstS = which ? bbfs : abfs;
  ushort* dstT = which ? bTs : aTs;
  float* dmean = which ? meanb : invmean;
  __shared__ __align__(16) ushort T[128][72];  // [d][l], padded
  __shared__ float accS[128];
  __shared__ float wgt[64];
  int t = threadIdx.x;
  if (t < 128) accS[t] = 0.f;
  if (t < 64)
    wgt[t] = which ? 1.0f : ((mask_b[bb * LL + l0 + t] == 0) ? 1.0f : 0.0f);
  int lrow = t >> 5;         // 0..7
  int dcol = (t & 31) * 4;   // 0..124
#pragma unroll
  for (int p = 0; p < 8; ++p) {
    int l = p * 8 + lrow;    // local row 0..63
    float4 v = *(const float4*)&src[((size_t)bb * LL + l0 + l) * HH + dcol];
    ushort4 u;
    u.x = f2bf(v.x); u.y = f2bf(v.y); u.z = f2bf(v.z); u.w = f2bf(v.w);
    int g = (l0 >> 4) + (l >> 4);
    int k = dcol >> 5, quadc = (dcol >> 3) & 3, j = dcol & 7;
    *(ushort4*)&dstS[chunkS(bb, g, k) + (size_t)(quadc * 16 + (l & 15)) * 8 + j] = u;
    T[dcol + 0][l] = u.x; T[dcol + 1][l] = u.y;
    T[dcol + 2][l] = u.z; T[dcol + 3][l] = u.w;
  }
  __syncthreads();
#pragma unroll
  for (int c = 0; c < 4; ++c) {
    int cid = c * 4 + (t >> 6);        // 0..15
    int dg = cid >> 1, mloc = cid & 1;
    int lane = t & 63, l16c = lane & 15, qc = lane >> 4;
    int row = dg * 16 + l16c, colb = mloc * 32 + qc * 8;
    uint2 vlo = *(const uint2*)&T[row][colb];
    uint2 vhi = *(const uint2*)&T[row][colb + 4];
    union { uint4 u4; short8 s8; ushort us[8]; } cv_;
    cv_.u4 = make_uint4(vlo.x, vlo.y, vhi.x, vhi.y);
    *(short8*)&dstT[chunkT(bb, dg, (l0 >> 5) + mloc) + (size_t)lane * 8] = cv_.s8;
    float s = 0.f;
#pragma unroll
    for (int jj = 0; jj < 8; ++jj) s += wgt[colb + jj] * bf2f(cv_.us[jj]);
    atomicAdd(&accS[row], s);
  }
  __syncthreads();
  if (t < 128) atomicAdd(&dmean[bb * HH + t], accS[t]);
}

// ---------------------------------------------------------------------------
// Batch-co-locating swizzle (R8-measured: FETCH 168 -> 38 MB):
// bid = 8*(tile + 16*(bb>>3)) + (bb&7); decode xcd=wg&7, k=wg>>3,
// tile=k&15, bb=(k>>4)*8+xcd.
// ---------------------------------------------------------------------------

// ---------------------------------------------------------------------------
// k_colsum: colsum[m] = sum_l exp(s[l][m]*temp + biasA[l] + biasB[m]).
// (unchanged, R11: chunked fragment loads; Pb-fold epilogue scales aTs.)
// grid 512 (1-D swizzled), block 256.
// ---------------------------------------------------------------------------
__global__ __launch_bounds__(256, 2) void k_colsum(
    const ushort* __restrict__ abfs, const ushort* __restrict__ bbfs,
    ushort* __restrict__ aTm,            // non-const: scaled in place
    const int* __restrict__ mask_a, const int* __restrict__ mask_b,
    const float* __restrict__ temp_p, float2* __restrict__ cc) {
  int wg = blockIdx.x;
  int xcd = wg & 7, k_ = wg >> 3;
  int bb = (k_ >> 4) * 8 + xcd;
  int m0 = (k_ & 15) * 64;
  int t = threadIdx.x;
  int w = t >> 6, lane = t & 63, l16 = lane & 15, quad = lane >> 4;
  float temp = temp_p[0];
  __shared__ __align__(16) float biasA[LL];
  __shared__ float csred[4][4][16];
  __shared__ float invS[64];
  for (int i = t; i < LL; i += 256)
    biasA[i] = mask_a[bb * LL + i] ? 0.0f : -10000.0f;

  short8 Bm[4][4];
  float biasB_mt[4];
#pragma unroll
  for (int mt = 0; mt < 4; ++mt) {
    int m = m0 + mt * 16 + l16;
    biasB_mt[mt] = mask_b[bb * LL + m] ? 0.0f : -10000.0f;
#pragma unroll
    for (int k = 0; k < 4; ++k)
      Bm[mt][k] = ld8(&bbfs[chunkS(bb, (m0 >> 4) + mt, k) + (size_t)lane * 8]);
  }
  __syncthreads();

  float cs[4] = {0.f, 0.f, 0.f, 0.f};
  short8 Al0[4], Al1[4];

#define LOADAL(AlX, IT)                                                       \
  {                                                                           \
    _Pragma("unroll") for (int k = 0; k < 4; ++k)                             \
        AlX[k] = ld8(&abfs[chunkS(bb, w * 16 + (IT), k) + (size_t)lane * 8]); \
  }

#define CSCOMPUTE(AlX, IT)                                                    \
  {                                                                           \
    int lbase = w * 256 + (IT) * 16;                                          \
    f32x4 bA = *(const f32x4*)&biasA[lbase + quad * 4];                       \
    _Pragma("unroll") for (int mt = 0; mt < 4; ++mt) {                        \
      f32x4 sacc = {0.f, 0.f, 0.f, 0.f};                                      \
      _Pragma("unroll") for (int k = 0; k < 4; ++k)                           \
          sacc = __builtin_amdgcn_mfma_f32_16x16x32_bf16(AlX[k], Bm[mt][k],   \
                                                         sacc, 0, 0, 0);      \
      _Pragma("unroll") for (int r = 0; r < 4; ++r)                           \
          cs[mt] += __expf(sacc[r] * temp + bA[r] + biasB_mt[mt]);            \
    }                                                                         \
  }

  LOADAL(Al0, 0);
  for (int it = 0; it < 16; it += 2) {
    LOADAL(Al1, it + 1);
    CSCOMPUTE(Al0, it);
    LOADAL(Al0, (it + 2) & 15);   // last prefetch wraps to 0 (unused, in-bounds)
    CSCOMPUTE(Al1, it + 1);
  }
#undef LOADAL
#undef CSCOMPUTE

#pragma unroll
  for (int mt = 0; mt < 4; ++mt) {
    cs[mt] += __shfl_xor(cs[mt], 16);
    cs[mt] += __shfl_xor(cs[mt], 32);
  }
  if (lane < 16) {
#pragma unroll
    for (int mt = 0; mt < 4; ++mt) csred[w][mt][l16] = cs[mt];
  }
  __syncthreads();
  if (t < 64) {
    int mt = t >> 4, ml = t & 15;
    float s = csred[0][mt][ml] + csred[1][mt][ml] + csred[2][mt][ml] + csred[3][mt][ml];
    int m = m0 + t;
    float bB = mask_b[bb * LL + m] ? 0.0f : -10000.0f;
    float inv = s > 0.f ? 1.0f / s : 0.0f;
    invS[t] = inv;
    cc[bb * LL + m] = make_float2(inv, bB);
  }
  __syncthreads();

  // ---- Pb-fold epilogue: scale this block's 16 aTs chunks in place ----
#pragma unroll
  for (int q = 0; q < 4; ++q) {
    int cid = q * 4 + (t >> 6);        // 0..15
    int dg = cid >> 1, mloc = cid & 1;
    int ln = t & 63;
    ushort* ap = &aTm[chunkT(bb, dg, (m0 >> 5) + mloc) + (size_t)ln * 8];
    short8 v = ld8(ap);
    int mb = mloc * 32 + (ln >> 4) * 8;   // m-offset within the 64-slice
    ushort o[8];
#pragma unroll
    for (int j = 0; j < 8; ++j) o[j] = f2bf(bf2f((ushort)v[j]) * invS[mb + j]);
    *(short8*)ap = *(short8*)&o[0];
  }
}

// ---------------------------------------------------------------------------
// k_features R14 = R11 exactly (measured best: 60 us, total 168.0):
//   chunk loads, single-P Pb-fold, S||F interleave with __syncthreads,
//   batch-co-locating swizzle, NT stores, l-tile 64, grid 512, lb(256,2).
// grid 512 (1-D swizzled), block 256.
// ---------------------------------------------------------------------------
__global__ __launch_bounds__(256, 2) void k_features(
    const ushort* __restrict__ abfs, const ushort* __restrict__ bbfs,
    const ushort* __restrict__ aTs, const ushort* __restrict__ bTs,
    const int* __restrict__ mask_a, const float* __restrict__ temp_p,
    const float2* __restrict__ cc, const float* __restrict__ meanb,
    const float* __restrict__ invmean, float* __restrict__ out) {
  int wg = blockIdx.x;
  int xcd = wg & 7, k_ = wg >> 3;
  int bb = (k_ >> 4) * 8 + xcd;
  int l0 = (k_ & 15) * 64;
  int t = threadIdx.x;
  int w = t >> 6, lane = t & 63, l16 = lane & 15, quad = lane >> 4;
  float temp = temp_p[0];

  __shared__ float2 ccs[LL];                        // 8 KB (only .y used)
  __shared__ __align__(16) ushort Pa[2][64 * 72];   // double-buffered, 18.4 KB
  __shared__ float rspart[4][64];
  __shared__ float rsfin[64];

  for (int i = t; i < LL; i += 256) ccs[i] = cc[bb * LL + i];

  float biasA_lt[4];
  short8 Afix[4][4];   // abf rows l0..l0+63 as B-operands (64 VGPRs)
#pragma unroll
  for (int lt = 0; lt < 4; ++lt) {
    int l = l0 + lt * 16 + l16;
    biasA_lt[lt] = mask_a[bb * LL + l] ? 0.0f : -10000.0f;
#pragma unroll
    for (int k = 0; k < 4; ++k)
      Afix[lt][k] = ld8(&abfs[chunkS(bb, (l0 >> 4) + lt, k) + (size_t)lane * 8]);
  }

  f32x4 accA[4][2], accB[4][2];
  f32x4 zero = {0.f, 0.f, 0.f, 0.f};
#pragma unroll
  for (int lt = 0; lt < 4; ++lt)
#pragma unroll
    for (int dt = 0; dt < 2; ++dt) { accA[lt][dt] = zero; accB[lt][dt] = zero; }
  float rs_lt[4] = {0.f, 0.f, 0.f, 0.f};
  __syncthreads();   // ccs ready

  short8 Am0[4], Am1[4];
  float cv0[4], cv1[4];                // biasB only
  short8 Bb0[2][2], Ba0[2][2], Bb1[2][2], Ba1[2][2];

#define LOADAM(AmX, cvX, M0)                                                  \
  {                                                                           \
    _Pragma("unroll") for (int k = 0; k < 4; ++k)                             \
        AmX[k] = ld8(&bbfs[chunkS(bb, ((M0) >> 4) + w, k) + (size_t)lane * 8]); \
    _Pragma("unroll") for (int r = 0; r < 4; ++r)                             \
        cvX[r] = ccs[(M0) + w * 16 + quad * 4 + r].y;                         \
  }

#define LOADBT(BbX, BaX, M0)                                                  \
  {                                                                           \
    _Pragma("unroll") for (int dt = 0; dt < 2; ++dt) {                        \
      _Pragma("unroll") for (int ks = 0; ks < 2; ++ks) {                      \
        size_t cb = chunkT(bb, w * 2 + dt, ((M0) >> 5) + ks) + (size_t)lane * 8; \
        BbX[dt][ks] = ld8(&bTs[cb]);                                          \
        BaX[dt][ks] = ld8(&aTs[cb]);                                          \
      }                                                                       \
    }                                                                         \
  }

// S-phase writing P[PBUFI] (single Pa buffer: e only)
#define SPHASE(AmX, cvX, PBUFI)                                               \
  {                                                                           \
    ushort* pa = &Pa[PBUFI][0];                                               \
    _Pragma("unroll") for (int lt = 0; lt < 4; ++lt) {                        \
      f32x4 sacc = zero;                                                      \
      _Pragma("unroll") for (int k = 0; k < 4; ++k)                           \
          sacc = __builtin_amdgcn_mfma_f32_16x16x32_bf16(AmX[k], Afix[lt][k], \
                                                         sacc, 0, 0, 0);      \
      ushort pav[4];                                                          \
      _Pragma("unroll") for (int r = 0; r < 4; ++r) {                         \
        float e = __expf(sacc[r] * temp + biasA_lt[lt] + cvX[r]);             \
        pav[r] = f2bf(e);                                                     \
        rs_lt[lt] += bf2f(pav[r]);                                            \
      }                                                                       \
      uint2 ka;                                                               \
      ka.x = (uint)pav[0] | ((uint)pav[1] << 16);                             \
      ka.y = (uint)pav[2] | ((uint)pav[3] << 16);                             \
      int pidx = (lt * 16 + l16) * 72 + w * 16 + quad * 4;                    \
      *(uint2*)&pa[pidx] = ka;                                                \
    }                                                                         \
  }

// F-phase reading P[PBUFI]; PaF shared by accA (x Bb) and accB (x Ba)
#define FPHASE(PBUFI, BbX, BaX)                                               \
  {                                                                           \
    const ushort* pa = &Pa[PBUFI][0];                                         \
    _Pragma("unroll") for (int lt = 0; lt < 4; ++lt) {                        \
      _Pragma("unroll") for (int ks = 0; ks < 2; ++ks) {                      \
        int ridx = (lt * 16 + l16) * 72 + ks * 32 + quad * 8;                 \
        short8 PaF = *(const short8*)&pa[ridx];                               \
        _Pragma("unroll") for (int dt = 0; dt < 2; ++dt) {                    \
          accA[lt][dt] = __builtin_amdgcn_mfma_f32_16x16x32_bf16(             \
              PaF, BbX[dt][ks], accA[lt][dt], 0, 0, 0);                       \
          accB[lt][dt] = __builtin_amdgcn_mfma_f32_16x16x32_bf16(             \
              PaF, BaX[dt][ks], accB[lt][dt], 0, 0, 0);                       \
        }                                                                     \
      }                                                                       \
    }                                                                         \
  }

  // ---- prologue: S(T0) -> P[0] ----
  LOADAM(Am0, cv0, 0);
  LOADBT(Bb0, Ba0, 0);            // F operands tile 0 (consumed next interval)
  LOADAM(Am1, cv1, 64);           // S operands tile 1
  SPHASE(Am0, cv0, 0);
  __syncthreads();

  // ---- main loop: 7x {S(T_{2k+1})+F(T_{2k}); S(T_{2k+2})+F(T_{2k+1})} ----
  for (int kk = 0; kk < 7; ++kk) {
    int mA = (2 * kk + 1) * 64;
    LOADBT(Bb1, Ba1, mA);
    LOADAM(Am0, cv0, mA + 64);
    SPHASE(Am1, cv1, 1);
    FPHASE(0, Bb0, Ba0);
    __syncthreads();
    LOADBT(Bb0, Ba0, mA + 64);
    LOADAM(Am1, cv1, mA + 128);   // k=6 -> T15
    SPHASE(Am0, cv0, 0);
    FPHASE(1, Bb1, Ba1);
    __syncthreads();
  }

  // ---- epilogue: S(T15) -> P[1]; F(T14); barrier; F(T15) ----
  LOADBT(Bb1, Ba1, 960);
  SPHASE(Am1, cv1, 1);
  FPHASE(0, Bb0, Ba0);
  __syncthreads();
  FPHASE(1, Bb1, Ba1);

#undef LOADAM
#undef LOADBT
#undef SPHASE
#undef FPHASE

  // ---- rowsum cross-wave reduce ----
#pragma unroll
  for (int lt = 0; lt < 4; ++lt) {
    rs_lt[lt] += __shfl_xor(rs_lt[lt], 16);
    rs_lt[lt] += __shfl_xor(rs_lt[lt], 32);
  }
  if (lane < 16) {
#pragma unroll
    for (int lt = 0; lt < 4; ++lt) rspart[w][lt * 16 + l16] = rs_lt[lt];
  }
  __syncthreads();
  if (t < 64)
    rsfin[t] = rspart[0][t] + rspart[1][t] + rspart[2][t] + rspart[3][t];
  __syncthreads();

  // ---- epilogue: NON-TEMPORAL stores (bypass L2, keep panels resident) ----
  float* outA = out;
  float* outB = out + (size_t)BN * LL * HH;
#pragma unroll
  for (int dt = 0; dt < 2; ++dt) {
    int d = w * 32 + dt * 16 + l16;
    float mb = meanb[bb * HH + d] * (1.0f / 1024.0f);
    float im = invmean[bb * HH + d] * (1.0f / 1024.0f);
#pragma unroll
    for (int lt = 0; lt < 4; ++lt) {
#pragma unroll
      for (int r = 0; r < 4; ++r) {
        int l = lt * 16 + quad * 4 + r;
        float rsv = rsfin[l];
        float fa = (rsv > 0.f) ? accA[lt][dt][r] / rsv : mb;
        float fb = accB[lt][dt][r] + im;
        __builtin_nontemporal_store(fa, &outA[((size_t)bb * LL + l0 + l) * HH + d]);
        __builtin_nontemporal_store(fb, &outB[((size_t)bb * LL + l0 + l) * HH + d]);
      }
    }
  }
}

// ---------------------------------------------------------------------------
extern "C" void kernel_launch(void* const* d_in, const int* in_sizes, int n_in,
                              void* d_out, int out_size, void* d_ws, size_t ws_size,
                              hipStream_t stream) {
  const float* a = (const float*)d_in[0];
  const float* b = (const float*)d_in[1];
  const int* mask_a = (const int*)d_in[2];
  const int* mask_b = (const int*)d_in[3];
  const float* temp = (const float*)d_in[4];
  float* out = (float*)d_out;

  char* wsb = (char*)d_ws;
  ushort* abfs = (ushort*)(wsb + 0 * SZ_BF);
  ushort* bbfs = (ushort*)(wsb + 1 * SZ_BF);
  ushort* aTs  = (ushort*)(wsb + 2 * SZ_BF);
  ushort* bTs  = (ushort*)(wsb + 3 * SZ_BF);
  float2* cc  = (float2*)(wsb + 4 * SZ_BF);
  float* meanb   = (float*)(wsb + 4 * SZ_BF + (size_t)BN * LL * sizeof(float2));
  float* invmean = meanb + BN * HH;

  hipMemsetAsync(meanb, 0, 2 * BN * HH * sizeof(float), stream);
  k_convert<<<dim3(16, 32, 2), 256, 0, stream>>>(a, b, mask_b, abfs, bbfs, aTs,
                                                 bTs, meanb, invmean);
  k_colsum<<<dim3(512), 256, 0, stream>>>(abfs, bbfs, aTs, mask_a, mask_b, temp, cc);
  k_features<<<dim3(512), 256, 0, stream>>>(abfs, bbfs, aTs, bTs, mask_a, temp,
                                            cc, meanb, invmean, out);
  (void)in_sizes; (void)n_in; (void)out_size; (void)ws_size;
}